// Round 1
// baseline (590.960 us; speedup 1.0000x reference)
//
#include <hip/hip_runtime.h>
#include <math.h>

// Problem constants (from reference)
#define B_   1024
#define T_   64
#define F_   18
#define U_   128
#define U3_  384   // 3*U
#define D_   64    // dense units

// One WAVE (64 threads) per batch element. Zero LDS, zero barriers.
//
// Key insight (carried over): the state table is indexed (id, b); the output
// depends only on the chain of timesteps t where id_t == id_63. On average
// that chain has ~1.06 steps, and h starts at exactly 0 (skip hz).
//
// New in this version:
//  - 64-thread blocks: each lane owns hidden units u and u+64. All
//    cross-lane communication is __shfl (uniform lane -> v_readlane), so
//    there are no __syncthreads and no LDS at all.
//  - The 64-iteration timestep scan (previously one ds_read_b32 of sid[t]
//    per iteration, ~120cy serial each) is replaced by ONE strided global
//    load (lane u reads id_u) + __ballot -> 64-bit match mask, walked with
//    ctz. Non-matching timesteps cost zero instructions.
//  - Summation order for xz (f ascending), hz (k = 0..127 ascending, two
//    passes) and dense (k ascending) preserved to keep bitwise parity with
//    the previous absmax==0.0 kernel.
__global__ __launch_bounds__(64) void feedzai_sync_gru_kernel(
    const float* __restrict__ inputs,      // [B, T, F]
    const float* __restrict__ sync_states, // [NIDS, B, U]
    const float* __restrict__ kernel_,     // [F, 3U]
    const float* __restrict__ rec_kernel,  // [U, 3U]
    const float* __restrict__ bias,        // [3U]
    const float* __restrict__ dense_w,     // [U, 64]
    const float* __restrict__ dense_b,     // [64]
    const float* __restrict__ out_w,       // [64, 1]
    const float* __restrict__ out_b,       // [1]
    float* __restrict__ out)               // [B, 1]
{
    const int b = blockIdx.x;
    const int u = threadIdx.x;   // 0..63

    const float* inp_b = inputs + (size_t)b * T_ * F_;

    // Lane u reads timestep u's id (column 0, stride F floats). T_ == 64.
    const int id_t = (int)inp_b[u * F_ + 0];
    const int id_last = __shfl(id_t, T_ - 1, 64);
    unsigned long long mask = __ballot(id_t == id_last);   // bit t set <=> step t is live

    // Initial h for this chain = sync_states[id_last, b, :]. 2 units/lane.
    const float* hptr = sync_states + ((size_t)id_last * B_ + b) * U_;
    float h0 = hptr[u];
    float h1 = hptr[u + 64];

    while (mask) {
        const int t = __builtin_ctzll(mask);   // ascending t: order preserved
        mask &= mask - 1;

        // x_t: lane f (< F_) holds x_t[f]; broadcast below via __shfl.
        const float xv_own = (u < F_) ? inp_b[t * F_ + u] : 0.0f;

        // xz = x_t @ kernel + bias, columns (z,r,h) x (u, u+64)
        float az0 = bias[u],           az1 = bias[u + 64];
        float ar0 = bias[U_ + u],      ar1 = bias[U_ + u + 64];
        float ah0 = bias[2 * U_ + u],  ah1 = bias[2 * U_ + u + 64];
        #pragma unroll
        for (int f = 0; f < F_; ++f) {
            const float xv = __shfl(xv_own, f, 64);
            const float* kf = kernel_ + f * U3_;
            az0 += xv * kf[u];            az1 += xv * kf[u + 64];
            ar0 += xv * kf[U_ + u];       ar1 += xv * kf[U_ + u + 64];
            ah0 += xv * kf[2 * U_ + u];   ah1 += xv * kf[2 * U_ + u + 64];
        }

        // hz = h @ rec_kernel — exactly zero when h == 0 (first live step,
        // since sync_states starts zeroed). Wave-vote, no LDS flag.
        float hz_z0 = 0.0f, hz_z1 = 0.0f;
        float hz_r0 = 0.0f, hz_r1 = 0.0f;
        float hz_h0 = 0.0f, hz_h1 = 0.0f;
        if (__ballot((h0 != 0.0f) || (h1 != 0.0f)) != 0ULL) {
            // k = 0..63 (h0 pass), then k = 64..127 (h1 pass): ascending order.
            for (int k = 0; k < 64; ++k) {
                const float hv = __shfl(h0, k, 64);
                const float* rk = rec_kernel + k * U3_;
                hz_z0 += hv * rk[u];            hz_z1 += hv * rk[u + 64];
                hz_r0 += hv * rk[U_ + u];       hz_r1 += hv * rk[U_ + u + 64];
                hz_h0 += hv * rk[2 * U_ + u];   hz_h1 += hv * rk[2 * U_ + u + 64];
            }
            for (int k = 0; k < 64; ++k) {
                const float hv = __shfl(h1, k, 64);
                const float* rk = rec_kernel + (k + 64) * U3_;
                hz_z0 += hv * rk[u];            hz_z1 += hv * rk[u + 64];
                hz_r0 += hv * rk[U_ + u];       hz_r1 += hv * rk[U_ + u + 64];
                hz_h0 += hv * rk[2 * U_ + u];   hz_h1 += hv * rk[2 * U_ + u + 64];
            }
        }

        // GRU cell (keras hard_sigmoid + tanh), two units per lane.
        const float z0 = fminf(fmaxf(0.2f * (az0 + hz_z0) + 0.5f, 0.0f), 1.0f);
        const float z1 = fminf(fmaxf(0.2f * (az1 + hz_z1) + 0.5f, 0.0f), 1.0f);
        const float r0 = fminf(fmaxf(0.2f * (ar0 + hz_r0) + 0.5f, 0.0f), 1.0f);
        const float r1 = fminf(fmaxf(0.2f * (ar1 + hz_r1) + 0.5f, 0.0f), 1.0f);
        const float hh0 = tanhf(ah0 + r0 * hz_h0);
        const float hh1 = tanhf(ah1 + r1 * hz_h1);
        h0 = z0 * h0 + (1.0f - z0) * hh0;
        h1 = z1 * h1 + (1.0f - z1) * hh1;
    }

    // Dense(128->64) + relu, then dot with out_w and sigmoid.
    // Lane u owns dense unit u. k ascending (two passes) preserves order.
    float dv = dense_b[u];
    for (int k = 0; k < 64; ++k) {
        const float hv = __shfl(h0, k, 64);
        dv += hv * dense_w[k * D_ + u];          // coalesced across u
    }
    for (int k = 0; k < 64; ++k) {
        const float hv = __shfl(h1, k, 64);
        dv += hv * dense_w[(k + 64) * D_ + u];
    }
    dv = fmaxf(dv, 0.0f);
    dv *= out_w[u];

    // reduce across the wave's 64 lanes
    #pragma unroll
    for (int off = 32; off > 0; off >>= 1)
        dv += __shfl_down(dv, off, 64);

    if (u == 0)
        out[b] = 1.0f / (1.0f + expf(-(dv + out_b[0])));
}

extern "C" void kernel_launch(void* const* d_in, const int* in_sizes, int n_in,
                              void* d_out, int out_size, void* d_ws, size_t ws_size,
                              hipStream_t stream) {
    const float* inputs      = (const float*)d_in[0];
    const float* sync_states = (const float*)d_in[1];
    const float* kernel_     = (const float*)d_in[2];
    const float* rec_kernel  = (const float*)d_in[3];
    const float* bias        = (const float*)d_in[4];
    const float* dense_w     = (const float*)d_in[5];
    const float* dense_b     = (const float*)d_in[6];
    const float* out_w       = (const float*)d_in[7];
    const float* out_b       = (const float*)d_in[8];
    float* out = (float*)d_out;

    feedzai_sync_gru_kernel<<<dim3(B_), dim3(64), 0, stream>>>(
        inputs, sync_states, kernel_, rec_kernel, bias,
        dense_w, dense_b, out_w, out_b, out);
}